// Round 8
// baseline (208.279 us; speedup 1.0000x reference)
//
#include <hip/hip_runtime.h>

// ---------------------------------------------------------------------------
// 2-layer GCN forward (PyG GCNConv) on MI355X, round 13b (R13 resubmit;
// R13's bench died at container level, no kernel-attributable evidence —
// same signature as R1, where an identical resubmit then passed).
//   out[d] = relu( p[d]*( sum_{s->d} p[s]*h[s] + p[d]*h[d] ) + b ),  h = x@W
// R13: agg1gemm2 v4 — attack the measured MLP bound.
//  - R11/R12 both 45.5us at 2.0 TB/s fabric: gather issued only 2 loads
//    deep per wave (1KB in flight/CU at ~500cy = ~2TB/s). Conflicts and
//    imbalance fixes (both landed per counters) changed nothing -> MLP bound.
//  - R13: (a) 8-deep gather batches (R7's shfl pattern) = 4x in-flight;
//    (b) B-fragments read DIRECT from w2t global (L2-resident 256KB) ->
//    no Bs staging, no 16 barriers (just 1), LDS 76.8->32KB;
//    (c) bias/adjacency from global; kt=0 B-frags prefetched pre-barrier.
//  - Accumulation order = R7 (self, then ELL, pads ps=0) -> same absmax.
// Floor analysis: gather 180MB logical; harness fill+restores ~58us.
// ---------------------------------------------------------------------------

typedef __bf16 bf16x8 __attribute__((ext_vector_type(8)));
typedef float floatx4 __attribute__((ext_vector_type(4)));
typedef unsigned short ushort_t;
typedef unsigned int uint_t;

#define MAXD 32

__device__ inline ushort_t f2bf(float f) {  // RNE fp32 -> bf16 bits
    unsigned u = __builtin_bit_cast(unsigned, f);
    unsigned r = (u + 0x7FFFu + ((u >> 16) & 1u)) >> 16;
    return (ushort_t)r;
}
__device__ inline float bf_lo(uint_t u) { return __builtin_bit_cast(float, u << 16); }
__device__ inline float bf_hi(uint_t u) { return __builtin_bit_cast(float, u & 0xFFFF0000u); }
__device__ inline uint_t pk2(float lo, float hi) {
    return (uint_t)f2bf(lo) | ((uint_t)f2bf(hi) << 16);
}

// [K][N] fp32 -> [N][K] bf16, one 32x32 tile per block (256 thr)
__device__ inline void transpose_tile(const float* __restrict__ in,
                                      ushort_t* __restrict__ out,
                                      int K, int N, int k0, int n0,
                                      ushort_t (*tile)[33]) {
    int tx = threadIdx.x & 31, ty = threadIdx.x >> 5;  // ty 0..7
    for (int r = ty; r < 32; r += 8)
        tile[r][tx] = f2bf(in[(size_t)(k0 + r) * N + n0 + tx]);
    __syncthreads();
    for (int r = ty; r < 32; r += 8)
        out[(size_t)(n0 + r) * K + k0 + tx] = tile[tx][r];
}

// Fused preprocessing: edge pass (deg count + ELL fill) | x->bf16 | W1^T | W2^T
__global__ __launch_bounds__(256) void prep_fused(
    const int* __restrict__ src, const int* __restrict__ dst,
    int* __restrict__ deg, int* __restrict__ col_ell,
    int* __restrict__ ovf_cnt, int* __restrict__ ovf, int e, int nb_e,
    const float* __restrict__ x, ushort_t* __restrict__ xb, long xcount, int nb_conv,
    const float* __restrict__ W1, ushort_t* __restrict__ w1t,
    const float* __restrict__ W2, ushort_t* __restrict__ w2t) {
    __shared__ ushort_t tile[32][33];
    int b = blockIdx.x;
    if (b < nb_e) {
        int i = b * 256 + threadIdx.x;
        if (i < e) {
            int s = src[i], d = dst[i];
            int slot = atomicAdd(&deg[d], 1);
            if (slot < MAXD) {
                col_ell[d * MAXD + slot] = s;
            } else {
                int k = atomicAdd(ovf_cnt, 1);
                ovf[2 * k] = d;
                ovf[2 * k + 1] = s;
            }
        }
        return;
    }
    b -= nb_e;
    if (b < nb_conv) {
        long i = ((long)b * 256 + threadIdx.x) * 4;
        if (i < xcount) {
            float4 v = *(const float4*)(x + i);
            ushort4 o = make_ushort4(f2bf(v.x), f2bf(v.y), f2bf(v.z), f2bf(v.w));
            *(ushort4*)(xb + i) = o;
        }
        return;
    }
    b -= nb_conv;
    if (b < 256) {  // W1: K=512, N=512 -> 16x16 tiles
        transpose_tile(W1, w1t, 512, 512, (b >> 4) * 32, (b & 15) * 32, tile);
        return;
    }
    b -= 256;       // W2: K=512, N=256 -> 8x16 tiles
    transpose_tile(W2, w2t, 512, 256, (b >> 3) * 32, (b & 7) * 32, tile);
}

// Layer-1 GEMM (+ dinv tail blocks).
// C[r][c] = bf16( sum_k A[r][k]*BT[c][k] ),  A:[M][K], BT:[N][K] bf16.
// 128x128 tile, BK=64, 4 waves, 4x4 16x16x32 frags.
// LDS swizzle: position s (16B chunks, 8/row) holds global granule s^(r&7).
__global__ __launch_bounds__(256) void gemm_mfma(
    const ushort_t* __restrict__ A, const ushort_t* __restrict__ BT,
    ushort_t* __restrict__ C,
    int M, int N, int K, int nbx, int gemm_blocks,
    const int* __restrict__ deg, float* __restrict__ dinv_out, int n) {
    __shared__ __align__(16) ushort_t As[8192];  // 128 rows x 64 k
    __shared__ __align__(16) ushort_t Bs[8192];

    if ((int)blockIdx.x >= gemm_blocks) {  // ---- dinv tail ----
        int i = ((int)blockIdx.x - gemm_blocks) * 256 + threadIdx.x;
        if (i < n) dinv_out[i] = 1.0f / sqrtf((float)(deg[i] + 1));
        return;
    }

    const int bx = (int)blockIdx.x % nbx, by = (int)blockIdx.x / nbx;
    const int tid = threadIdx.x;
    const int w = tid >> 6, lane = tid & 63;
    const int q = lane >> 4, ml = lane & 15;
    const int wm = (w >> 1) * 64, wn = (w & 1) * 64;
    const int row0 = by * 128, col0 = bx * 128;

    // staging: lane L covers row sub = L>>3, granule gsw = (L&7)^((L>>3)&7)
    const int rr = lane >> 3;                  // 0..7
    const int gsw = (lane & 7) ^ (rr & 7);     // global k-granule (x8 ushorts)
    const ushort_t* ga[4];
    const ushort_t* gb[4];
    ushort_t* la[4];
    ushort_t* lb[4];
#pragma unroll
    for (int rp = 0; rp < 4; rp++) {
        int r = rp * 32 + w * 8 + rr;
        int gra = min(row0 + r, M - 1);
        ga[rp] = A + (size_t)gra * K + gsw * 8;
        gb[rp] = BT + (size_t)(col0 + r) * K + gsw * 8;
        la[rp] = As + rp * 2048 + w * 512;  // wave-uniform; HW adds lane*16B
        lb[rp] = Bs + rp * 2048 + w * 512;
    }

    // fragment read offsets (ushort idx): row_loc*64 + ((g ^ (ml&7))*8)
    const int sel = ml & 7;
    int aoff[2][4], boff[2][4];
#pragma unroll
    for (int st = 0; st < 2; st++)
#pragma unroll
        for (int i = 0; i < 4; i++) {
            int g = q + st * 4;
            aoff[st][i] = (wm + i * 16 + ml) * 64 + ((g ^ sel) << 3);
            boff[st][i] = (wn + i * 16 + ml) * 64 + ((g ^ sel) << 3);
        }

    floatx4 acc[4][4];
#pragma unroll
    for (int i = 0; i < 4; i++)
#pragma unroll
        for (int j = 0; j < 4; j++) acc[i][j] = (floatx4)0.0f;

    for (int kt = 0; kt < K; kt += 64) {
#pragma unroll
        for (int rp = 0; rp < 4; rp++) {
            __builtin_amdgcn_global_load_lds(
                (const __attribute__((address_space(1))) unsigned*)ga[rp],
                (__attribute__((address_space(3))) unsigned*)la[rp], 16, 0, 0);
            __builtin_amdgcn_global_load_lds(
                (const __attribute__((address_space(1))) unsigned*)gb[rp],
                (__attribute__((address_space(3))) unsigned*)lb[rp], 16, 0, 0);
            ga[rp] += 64; gb[rp] += 64;
        }
        __syncthreads();
#pragma unroll
        for (int st = 0; st < 2; st++) {
            bf16x8 af[4], bfr[4];
#pragma unroll
            for (int i = 0; i < 4; i++) {
                af[i] = *(const bf16x8*)(As + aoff[st][i]);
                bfr[i] = *(const bf16x8*)(Bs + boff[st][i]);
            }
#pragma unroll
            for (int i = 0; i < 4; i++)
#pragma unroll
                for (int j = 0; j < 4; j++)
                    acc[i][j] = __builtin_amdgcn_mfma_f32_16x16x32_bf16(
                        af[i], bfr[j], acc[i][j], 0, 0, 0);
        }
        __syncthreads();
    }

    // epilogue: C/D layout col=lane&15, row=q*4+reg  [m89/m91]; store bf16
#pragma unroll
    for (int i = 0; i < 4; i++) {
        int rbase = row0 + wm + i * 16 + q * 4;
#pragma unroll
        for (int j = 0; j < 4; j++) {
            int gc = col0 + wn + j * 16 + ml;
#pragma unroll
            for (int r = 0; r < 4; r++) {
                int gr = rbase + r;
                if (gr < M) C[(size_t)gr * N + gc] = f2bf(acc[i][j][r]);
            }
        }
    }
}

// FUSED aggregate1 + layer-2 GEMM, v4: 8-deep gather, direct-global B.
// h1[r][k] = relu(pd_r*(pd_r*g[r][k] + sum ps*g[s][k]) + b1[k]).
// BM=32 rows, 512 thr (8 waves). Pass p: wave w gathers row p*8+w with
// R7's pattern (32 ELL cols in lanes 0-31, shfl broadcast, 8 loads/batch,
// pads ps=0). h1 -> As (swizzled, 32KB, only LDS). ONE barrier. MFMA phase
// reads B-fragments directly from w2t (L2-resident): lane(q,ml) reads 16B
// at BT[(wn+j*16+ml)*512 + kt*64 + st*32 + q*8] — same data Bs staging
// delivered. g2[r][c] = bf16(dinv[r]*(h1@W2)[r][c]) (pre-scaled for agg2).
__global__ __launch_bounds__(512, 4) void agg1gemm2(
    const ushort_t* __restrict__ g,    // [n][512] bf16 (unscaled x@W1)
    const ushort_t* __restrict__ BT,   // w2t [256][512] bf16
    const int* __restrict__ deg, const int* __restrict__ col_ell,
    const int* __restrict__ ovf_cnt, const int* __restrict__ ovf,
    const float* __restrict__ dinv, const float* __restrict__ b1,
    ushort_t* __restrict__ g2, int M) {
    __shared__ __align__(16) ushort_t As[32 * 512];   // 32 KB (only LDS)

    const int tid = threadIdx.x;
    const int w = tid >> 6, lane = tid & 63;
    const int q = lane >> 4, ml = lane & 15;
    const int wm = (w >> 2) * 16, wn = (w & 3) * 64;
    const int row0 = (int)blockIdx.x * 32;

    const int nov = *ovf_cnt;  // ~always 0
    const int c = lane;        // k-granule 0..63 (feats c*8..c*8+7)

    // bias for this thread's 8 feats (global, L2-hot)
    float4 bv0 = *(const float4*)(b1 + c * 8);
    float4 bv1 = *(const float4*)(b1 + c * 8 + 4);

    // ---- gather: 4 passes, 1 row per wave per pass, 8-deep batches ----
#pragma unroll
    for (int p = 0; p < 4; p++) {
        const int lr = p * 8 + w;
        const int rP = min(row0 + lr, M - 1);
        const int cnt = min(deg[rP], MAXD);
        const float pd = dinv[rP];

        // adjacency into lanes 0..31 (R7 pattern); pads -> self, ps=0
        int cv = rP;
        float dv = 0.0f;
        if (lane < cnt) {
            cv = col_ell[(size_t)rP * MAXD + lane];
            dv = dinv[cv];
        }

        // self term first (exact R7 order)
        uint4 us = *(const uint4*)(g + (size_t)rP * 512 + c * 8);
        float a0 = pd * bf_lo(us.x), a1 = pd * bf_hi(us.x);
        float a2 = pd * bf_lo(us.y), a3 = pd * bf_hi(us.y);
        float a4 = pd * bf_lo(us.z), a5 = pd * bf_hi(us.z);
        float a6 = pd * bf_lo(us.w), a7 = pd * bf_hi(us.w);

        for (int e0 = 0; e0 < cnt; e0 += 8) {
            uint4 u[8];
            float ps[8];
#pragma unroll
            for (int j = 0; j < 8; j++) {
                int s = __shfl(cv, e0 + j);
                ps[j] = __shfl(dv, e0 + j);
                u[j] = *(const uint4*)(g + (size_t)s * 512 + c * 8);
            }
#pragma unroll
            for (int j = 0; j < 8; j++) {
                a0 = fmaf(ps[j], bf_lo(u[j].x), a0);
                a1 = fmaf(ps[j], bf_hi(u[j].x), a1);
                a2 = fmaf(ps[j], bf_lo(u[j].y), a2);
                a3 = fmaf(ps[j], bf_hi(u[j].y), a3);
                a4 = fmaf(ps[j], bf_lo(u[j].z), a4);
                a5 = fmaf(ps[j], bf_hi(u[j].z), a5);
                a6 = fmaf(ps[j], bf_lo(u[j].w), a6);
                a7 = fmaf(ps[j], bf_hi(u[j].w), a7);
            }
        }
        for (int k2 = 0; k2 < nov; k2++) {  // ~never taken
            if (ovf[2 * k2] == rP) {
                int sI = ovf[2 * k2 + 1];
                float ps = dinv[sI];
                uint4 u = *(const uint4*)(g + (size_t)sI * 512 + c * 8);
                a0 = fmaf(ps, bf_lo(u.x), a0);
                a1 = fmaf(ps, bf_hi(u.x), a1);
                a2 = fmaf(ps, bf_lo(u.y), a2);
                a3 = fmaf(ps, bf_hi(u.y), a3);
                a4 = fmaf(ps, bf_lo(u.z), a4);
                a5 = fmaf(ps, bf_hi(u.z), a5);
                a6 = fmaf(ps, bf_lo(u.w), a6);
                a7 = fmaf(ps, bf_hi(u.w), a7);
            }
        }
        float h0 = fmaxf(fmaf(pd, a0, bv0.x), 0.0f);
        float h1 = fmaxf(fmaf(pd, a1, bv0.y), 0.0f);
        float h2 = fmaxf(fmaf(pd, a2, bv0.z), 0.0f);
        float h3 = fmaxf(fmaf(pd, a3, bv0.w), 0.0f);
        float h4 = fmaxf(fmaf(pd, a4, bv1.x), 0.0f);
        float h5 = fmaxf(fmaf(pd, a5, bv1.y), 0.0f);
        float h6 = fmaxf(fmaf(pd, a6, bv1.z), 0.0f);
        float h7 = fmaxf(fmaf(pd, a7, bv1.w), 0.0f);
        uint4 U;
        U.x = pk2(h0, h1);
        U.y = pk2(h2, h3);
        U.z = pk2(h4, h5);
        U.w = pk2(h6, h7);
        int pos = (c & ~7) | ((c & 7) ^ (lr & 7));
        *(uint4*)(As + lr * 512 + pos * 8) = U;
    }

    // ---- B-fragment pointers (direct global) + kt=0 prefetch pre-barrier ----
    const ushort_t* bp[4];
#pragma unroll
    for (int j = 0; j < 4; j++)
        bp[j] = BT + (size_t)(wn + j * 16 + ml) * 512 + q * 8;

    bf16x8 bfr[2][4];
#pragma unroll
    for (int st = 0; st < 2; st++)
#pragma unroll
        for (int j = 0; j < 4; j++)
            bfr[st][j] = *(const bf16x8*)(bp[j] + st * 32);

    __syncthreads();  // As complete (the only barrier)

    // ---- MFMA phase: no barriers; As via swizzled ds_read, B 2-deep ----
    const int sel = ml & 7;
    int aoffb[2];
#pragma unroll
    for (int st = 0; st < 2; st++)
        aoffb[st] = (wm + ml) * 512 + (((st * 4 + q) ^ sel) << 3);

    floatx4 accm[4];
#pragma unroll
    for (int j = 0; j < 4; j++) accm[j] = (floatx4)0.0f;

    for (int kt = 0; kt < 8; kt++) {
        bf16x8 nb[2][4];
        if (kt < 7) {
#pragma unroll
            for (int st = 0; st < 2; st++)
#pragma unroll
                for (int j = 0; j < 4; j++)
                    nb[st][j] = *(const bf16x8*)(bp[j] + (kt + 1) * 64 + st * 32);
        }
#pragma unroll
        for (int st = 0; st < 2; st++) {
            bf16x8 af = *(const bf16x8*)(As + aoffb[st] + kt * 64);
#pragma unroll
            for (int j = 0; j < 4; j++)
                accm[j] = __builtin_amdgcn_mfma_f32_16x16x32_bf16(
                    af, bfr[st][j], accm[j], 0, 0, 0);
        }
#pragma unroll
        for (int st = 0; st < 2; st++)
#pragma unroll
            for (int j = 0; j < 4; j++) bfr[st][j] = nb[st][j];
    }

    // epilogue: C 32x256; row=wm+q*4+r, col=wn+j*16+ml; scale by dinv
#pragma unroll
    for (int rg = 0; rg < 4; rg++) {
        int grow = row0 + wm + q * 4 + rg;
        float pd = (grow < M) ? dinv[grow] : 1.0f;
#pragma unroll
        for (int j = 0; j < 4; j++) {
            int gcx = wn + j * 16 + ml;
            if (grow < M)
                g2[(size_t)grow * 256 + gcx] = f2bf(pd * accm[j][rg]);
        }
    }
}

// Layer-2 aggregate over PRE-SCALED g2: out = relu(pd*(g[d]+sum g[s]) + b)
// g: [n][256] bf16 as uint2; one wave per node; cols preloaded once.
__global__ __launch_bounds__(64) void aggregate2(const uint2* __restrict__ g,
                                                 const int* __restrict__ deg,
                                                 const int* __restrict__ col_ell,
                                                 const int* __restrict__ ovf_cnt,
                                                 const int* __restrict__ ovf,
                                                 const float* __restrict__ dinv,
                                                 const float* __restrict__ bias,
                                                 float* __restrict__ out) {
    const int d = blockIdx.x, t = threadIdx.x;
    const int cnt = min(deg[d], MAXD);
    const float pd = dinv[d];
    const size_t base = (size_t)d * 64 + t;
    const int* cm = col_ell + (size_t)d * MAXD;

    int cv = 0;
    float wv = 0.0f;
    if (t < MAXD && t < cnt) {
        cv = cm[t];
        wv = 1.0f;
    }
    float4 b = *(const float4*)(bias + t * 4);

    uint2 us = g[base];
    float a0 = bf_lo(us.x), a1 = bf_hi(us.x);
    float a2 = bf_lo(us.y), a3 = bf_hi(us.y);  // self term

    for (int e0 = 0; e0 < cnt; e0 += 8) {
        uint2 u[8];
        float ws[8];
#pragma unroll
        for (int j = 0; j < 8; j++) {
            int s = __shfl(cv, e0 + j);
            ws[j] = __shfl(wv, e0 + j);
            u[j] = g[(size_t)s * 64 + t];
        }
#pragma unroll
        for (int j = 0; j < 8; j++) {
            a0 = fmaf(ws[j], bf_lo(u[j].x), a0);
            a1 = fmaf(ws[j], bf_hi(u[j].x), a1);
            a2 = fmaf(ws[j], bf_lo(u[j].y), a2);
            a3 = fmaf(ws[j], bf_hi(u[j].y), a3);
        }
    }
    int nov = *ovf_cnt;  // ~always 0
    for (int k = 0; k < nov; k++) {
        if (ovf[2 * k] == d) {
            uint2 u = g[(size_t)ovf[2 * k + 1] * 64 + t];
            a0 += bf_lo(u.x); a1 += bf_hi(u.x);
            a2 += bf_lo(u.y); a3 += bf_hi(u.y);
        }
    }
    float4 o;
    o.x = fmaxf(fmaf(pd, a0, b.x), 0.0f);
    o.y = fmaxf(fmaf(pd, a1, b.y), 0.0f);
    o.z = fmaxf(fmaf(pd, a2, b.z), 0.0f);
    o.w = fmaxf(fmaf(pd, a3, b.w), 0.0f);
    *(float4*)(out + (size_t)d * 256 + t * 4) = o;
}

extern "C" void kernel_launch(void* const* d_in, const int* in_sizes, int n_in,
                              void* d_out, int out_size, void* d_ws, size_t ws_size,
                              hipStream_t stream) {
    const float* x  = (const float*)d_in[0];
    const int*   ei = (const int*)d_in[1];   // int32 on device
    const float* W1 = (const float*)d_in[2];
    const float* b1 = (const float*)d_in[3];
    const float* W2 = (const float*)d_in[4];
    const float* b2 = (const float*)d_in[5];
    float* out = (float*)d_out;

    const int FIN = 512, FH = 512, FOUT = 256;
    const int n = in_sizes[0] / FIN;  // 20000
    const int e = in_sizes[1] / 2;    // 160000
    const int* src = ei;
    const int* dst = ei + e;

    auto align_up = [](size_t v) { return (v + 255) & ~(size_t)255; };
    char* w = (char*)d_ws;
    int*      deg     = (int*)w;                 // deg[n] + ovf_cnt adjacent
    int*      ovf_cnt = deg + n;
    w += align_up((size_t)(n + 1) * 4);
    float*    dinv    = (float*)w;    w += align_up((size_t)n * 4);
    int*      col_ell = (int*)w;      w += align_up((size_t)n * MAXD * 4);
    int*      ovf     = (int*)w;      w += align_up((size_t)2048 * 4);
    ushort_t* xb      = (ushort_t*)w; w += align_up((size_t)n * FIN * 2);
    ushort_t* w1t     = (ushort_t*)w; w += align_up((size_t)FH * FIN * 2);
    ushort_t* w2t     = (ushort_t*)w; w += align_up((size_t)FOUT * FH * 2);
    ushort_t* g       = (ushort_t*)w; w += align_up((size_t)n * FH * 2);   // x@W1
    ushort_t* g2      = (ushort_t*)w; w += align_up((size_t)n * FOUT * 2); // scaled h1@W2

    const int nb_n = (n + 255) / 256;
    const int nb_e = (e + 255) / 256;
    const long xcount = (long)n * FIN;
    const int nb_conv = (int)((xcount / 4 + 255) / 256);

    hipMemsetAsync(deg, 0, (size_t)(n + 1) * 4, stream);  // deg + ovf_cnt

    prep_fused<<<nb_e + nb_conv + 256 + 128, 256, 0, stream>>>(
        src, dst, deg, col_ell, ovf_cnt, ovf, e, nb_e,
        x, xb, xcount, nb_conv, W1, w1t, W2, w2t);

    // layer 1 GEMM (unscaled) + dinv tail blocks
    {
        const int mb = (n + 127) / 128;
        int gemm_blocks = (FH / 128) * mb;
        gemm_mfma<<<gemm_blocks + nb_n, 256, 0, stream>>>(
            xb, w1t, g, n, FH, FIN, FH / 128, gemm_blocks, deg, dinv, n);
    }
    // fused aggregate1 + layer-2 GEMM (writes pre-scaled g2)
    agg1gemm2<<<(n + 31) / 32, 512, 0, stream>>>(
        g, w2t, deg, col_ell, ovf_cnt, ovf, dinv, b1, g2, n);

    aggregate2<<<n, 64, 0, stream>>>((const uint2*)g2, deg, col_ell, ovf_cnt,
                                     ovf, dinv, b2, out);

    (void)ws_size; (void)n_in; (void)out_size;
}

// Round 9
// 180.261 us; speedup vs baseline: 1.1554x; 1.1554x over previous
//
#include <hip/hip_runtime.h>

// ---------------------------------------------------------------------------
// 2-layer GCN forward (PyG GCNConv) on MI355X, round 14.
//   out[d] = relu( p[d]*( sum_{s->d} p[s]*h[s] + p[d]*h[d] ) + b ),  h = x@W
// R14 = R12 (proven 181.0us total, agg1gemm2 45.5us) + ONE change:
//   gather batches 2-deep -> 8-deep (adjacency still from LDS adj_s).
// R13 post-mortem (measured 77us, REGRESSION): it changed 3 things at once;
//   per-pass inline adjacency (serial dep chain deg->col_ell->dinv-gather
//   per pass, VALUBusy 20->11%) and uncoalesced direct-global B (16 lines
//   per frag-load) swamped any batching gain. Reverted both; batching gets
//   a clean single-variable test here.
// Hypothesis: R12's 2.0 TB/s gather = 2-deep MLP limit; 8-deep -> 2.8-4 TB/s,
//   agg1gemm2 -> 33-38us. If unchanged: latency floor at 625 blocks ->
//   fused ceiling reached, revert to R12 next.
// ---------------------------------------------------------------------------

typedef __bf16 bf16x8 __attribute__((ext_vector_type(8)));
typedef float floatx4 __attribute__((ext_vector_type(4)));
typedef unsigned short ushort_t;
typedef unsigned int uint_t;

#define MAXD 32
#define CAP 40  // self + 32 ELL + pad-to-x8 (pads: ps=0, col=self -> hot)

__device__ inline ushort_t f2bf(float f) {  // RNE fp32 -> bf16 bits
    unsigned u = __builtin_bit_cast(unsigned, f);
    unsigned r = (u + 0x7FFFu + ((u >> 16) & 1u)) >> 16;
    return (ushort_t)r;
}
__device__ inline float bf_lo(uint_t u) { return __builtin_bit_cast(float, u << 16); }
__device__ inline float bf_hi(uint_t u) { return __builtin_bit_cast(float, u & 0xFFFF0000u); }
__device__ inline uint_t pk2(float lo, float hi) {
    return (uint_t)f2bf(lo) | ((uint_t)f2bf(hi) << 16);
}

// [K][N] fp32 -> [N][K] bf16, one 32x32 tile per block (256 thr)
__device__ inline void transpose_tile(const float* __restrict__ in,
                                      ushort_t* __restrict__ out,
                                      int K, int N, int k0, int n0,
                                      ushort_t (*tile)[33]) {
    int tx = threadIdx.x & 31, ty = threadIdx.x >> 5;  // ty 0..7
    for (int r = ty; r < 32; r += 8)
        tile[r][tx] = f2bf(in[(size_t)(k0 + r) * N + n0 + tx]);
    __syncthreads();
    for (int r = ty; r < 32; r += 8)
        out[(size_t)(n0 + r) * K + k0 + tx] = tile[tx][r];
}

// Fused preprocessing: edge pass (deg count + ELL fill) | x->bf16 | W1^T | W2^T
__global__ __launch_bounds__(256) void prep_fused(
    const int* __restrict__ src, const int* __restrict__ dst,
    int* __restrict__ deg, int* __restrict__ col_ell,
    int* __restrict__ ovf_cnt, int* __restrict__ ovf, int e, int nb_e,
    const float* __restrict__ x, ushort_t* __restrict__ xb, long xcount, int nb_conv,
    const float* __restrict__ W1, ushort_t* __restrict__ w1t,
    const float* __restrict__ W2, ushort_t* __restrict__ w2t) {
    __shared__ ushort_t tile[32][33];
    int b = blockIdx.x;
    if (b < nb_e) {
        int i = b * 256 + threadIdx.x;
        if (i < e) {
            int s = src[i], d = dst[i];
            int slot = atomicAdd(&deg[d], 1);
            if (slot < MAXD) {
                col_ell[d * MAXD + slot] = s;
            } else {
                int k = atomicAdd(ovf_cnt, 1);
                ovf[2 * k] = d;
                ovf[2 * k + 1] = s;
            }
        }
        return;
    }
    b -= nb_e;
    if (b < nb_conv) {
        long i = ((long)b * 256 + threadIdx.x) * 4;
        if (i < xcount) {
            float4 v = *(const float4*)(x + i);
            ushort4 o = make_ushort4(f2bf(v.x), f2bf(v.y), f2bf(v.z), f2bf(v.w));
            *(ushort4*)(xb + i) = o;
        }
        return;
    }
    b -= nb_conv;
    if (b < 256) {  // W1: K=512, N=512 -> 16x16 tiles
        transpose_tile(W1, w1t, 512, 512, (b >> 4) * 32, (b & 15) * 32, tile);
        return;
    }
    b -= 256;       // W2: K=512, N=256 -> 8x16 tiles
    transpose_tile(W2, w2t, 512, 256, (b >> 3) * 32, (b & 7) * 32, tile);
}

// Layer-1 GEMM (+ dinv tail blocks).
// C[r][c] = bf16( sum_k A[r][k]*BT[c][k] ),  A:[M][K], BT:[N][K] bf16.
// 128x128 tile, BK=64, 4 waves, 4x4 16x16x32 frags.
// LDS swizzle: position s (16B chunks, 8/row) holds global granule s^(r&7).
__global__ __launch_bounds__(256) void gemm_mfma(
    const ushort_t* __restrict__ A, const ushort_t* __restrict__ BT,
    ushort_t* __restrict__ C,
    int M, int N, int K, int nbx, int gemm_blocks,
    const int* __restrict__ deg, float* __restrict__ dinv_out, int n) {
    __shared__ __align__(16) ushort_t As[8192];  // 128 rows x 64 k
    __shared__ __align__(16) ushort_t Bs[8192];

    if ((int)blockIdx.x >= gemm_blocks) {  // ---- dinv tail ----
        int i = ((int)blockIdx.x - gemm_blocks) * 256 + threadIdx.x;
        if (i < n) dinv_out[i] = 1.0f / sqrtf((float)(deg[i] + 1));
        return;
    }

    const int bx = (int)blockIdx.x % nbx, by = (int)blockIdx.x / nbx;
    const int tid = threadIdx.x;
    const int w = tid >> 6, lane = tid & 63;
    const int q = lane >> 4, ml = lane & 15;
    const int wm = (w >> 1) * 64, wn = (w & 1) * 64;
    const int row0 = by * 128, col0 = bx * 128;

    // staging: lane L covers row sub = L>>3, granule gsw = (L&7)^((L>>3)&7)
    const int rr = lane >> 3;                  // 0..7
    const int gsw = (lane & 7) ^ (rr & 7);     // global k-granule (x8 ushorts)
    const ushort_t* ga[4];
    const ushort_t* gb[4];
    ushort_t* la[4];
    ushort_t* lb[4];
#pragma unroll
    for (int rp = 0; rp < 4; rp++) {
        int r = rp * 32 + w * 8 + rr;
        int gra = min(row0 + r, M - 1);
        ga[rp] = A + (size_t)gra * K + gsw * 8;
        gb[rp] = BT + (size_t)(col0 + r) * K + gsw * 8;
        la[rp] = As + rp * 2048 + w * 512;  // wave-uniform; HW adds lane*16B
        lb[rp] = Bs + rp * 2048 + w * 512;
    }

    // fragment read offsets (ushort idx): row_loc*64 + ((g ^ (ml&7))*8)
    const int sel = ml & 7;
    int aoff[2][4], boff[2][4];
#pragma unroll
    for (int st = 0; st < 2; st++)
#pragma unroll
        for (int i = 0; i < 4; i++) {
            int g = q + st * 4;
            aoff[st][i] = (wm + i * 16 + ml) * 64 + ((g ^ sel) << 3);
            boff[st][i] = (wn + i * 16 + ml) * 64 + ((g ^ sel) << 3);
        }

    floatx4 acc[4][4];
#pragma unroll
    for (int i = 0; i < 4; i++)
#pragma unroll
        for (int j = 0; j < 4; j++) acc[i][j] = (floatx4)0.0f;

    for (int kt = 0; kt < K; kt += 64) {
#pragma unroll
        for (int rp = 0; rp < 4; rp++) {
            __builtin_amdgcn_global_load_lds(
                (const __attribute__((address_space(1))) unsigned*)ga[rp],
                (__attribute__((address_space(3))) unsigned*)la[rp], 16, 0, 0);
            __builtin_amdgcn_global_load_lds(
                (const __attribute__((address_space(1))) unsigned*)gb[rp],
                (__attribute__((address_space(3))) unsigned*)lb[rp], 16, 0, 0);
            ga[rp] += 64; gb[rp] += 64;
        }
        __syncthreads();
#pragma unroll
        for (int st = 0; st < 2; st++) {
            bf16x8 af[4], bfr[4];
#pragma unroll
            for (int i = 0; i < 4; i++) {
                af[i] = *(const bf16x8*)(As + aoff[st][i]);
                bfr[i] = *(const bf16x8*)(Bs + boff[st][i]);
            }
#pragma unroll
            for (int i = 0; i < 4; i++)
#pragma unroll
                for (int j = 0; j < 4; j++)
                    acc[i][j] = __builtin_amdgcn_mfma_f32_16x16x32_bf16(
                        af[i], bfr[j], acc[i][j], 0, 0, 0);
        }
        __syncthreads();
    }

    // epilogue: C/D layout col=lane&15, row=q*4+reg  [m89/m91]; store bf16
#pragma unroll
    for (int i = 0; i < 4; i++) {
        int rbase = row0 + wm + i * 16 + q * 4;
#pragma unroll
        for (int j = 0; j < 4; j++) {
            int gc = col0 + wn + j * 16 + ml;
#pragma unroll
            for (int r = 0; r < 4; r++) {
                int gr = rbase + r;
                if (gr < M) C[(size_t)gr * N + gc] = f2bf(acc[i][j][r]);
            }
        }
    }
}

// FUSED aggregate1 + layer-2 GEMM, v5 = R12 + 8-deep gather batches.
// h1[r][k] = relu(pd_r*(pd_r*g[r][k] + sum ps*g[s][k]) + b1[k]).
// BM=32 rows, 512 thr (8 waves). Pass p (0..3): wave w handles row p*8+w;
// thread granule c = tid&63 owns feats [c*8, c*8+8). Per batch: read 8
// adjacency int2 from LDS, issue 8 full-row coalesced loads (64x16B each),
// then consume in order (same FMA order as R12 -> bit-identical). As write
// pos=(c&~7)|((c&7)^(r&7)) (2-way, free). Then 8 MFMA K-steps streaming Bs.
// g2[r][c] = bf16(dinv[r] * (h1 @ W2)[r][c])  (pre-scaled for agg2).
__global__ __launch_bounds__(512, 4) void agg1gemm2(
    const ushort_t* __restrict__ g,    // [n][512] bf16 (unscaled x@W1)
    const ushort_t* __restrict__ BT,   // w2t [256][512] bf16
    const int* __restrict__ deg, const int* __restrict__ col_ell,
    const int* __restrict__ ovf_cnt, const int* __restrict__ ovf,
    const float* __restrict__ dinv, const float* __restrict__ b1,
    ushort_t* __restrict__ g2, int M) {
    __shared__ __align__(16) ushort_t As[32 * 512];   // 32 KB (full-K h1 tile)
    __shared__ __align__(16) ushort_t Bs[256 * 64];   // 32 KB (per-kt B tile)
    __shared__ int2  adj_s[32][CAP];                  // 10 KB (.x=col,.y=ps)
    __shared__ float b1_s[512];                       //  2 KB
    __shared__ int   cnt_s[32];

    const int tid = threadIdx.x;
    const int w = tid >> 6, lane = tid & 63;
    const int q = lane >> 4, ml = lane & 15;
    const int wm = (w >> 2) * 16, wn = (w & 3) * 64;
    const int row0 = (int)blockIdx.x * 32;

    // ---- prologue: bias + adjacency (slot0=self/pd; pads col=self, ps=0) ----
    b1_s[tid] = b1[tid];
    {
        int r = tid >> 4, jj = tid & 15;   // 16 threads per row
        int rg = min(row0 + r, M - 1);
        int cnt = min(deg[rg], MAXD);
        const int* cm = col_ell + (size_t)rg * MAXD;
#pragma unroll
        for (int pass = 0; pass < 3; pass++) {
            int j = jj + pass * 16;
            if (j >= CAP) break;
            int2 a;
            if (j == 0) {
                a.x = rg;
                a.y = __builtin_bit_cast(int, dinv[rg]);
                cnt_s[r] = cnt + 1;
            } else {
                bool vld = (j - 1) < cnt;
                int c = vld ? cm[j - 1] : rg;   // pad: self row (hot), weight 0
                a.x = c;
                a.y = vld ? __builtin_bit_cast(int, dinv[c]) : 0;
            }
            adj_s[r][j] = a;
        }
    }
    const int nov = *ovf_cnt;  // ~always 0
    __syncthreads();

    // ---- B staging pointers (global_load_lds, proven swizzle) ----
    const int rr = lane >> 3;
    const int gsw = (lane & 7) ^ (rr & 7);
    const ushort_t* gb[4];
    ushort_t* lb[4];
#pragma unroll
    for (int rp = 0; rp < 4; rp++) {
        gb[rp] = BT + (size_t)(rp * 64 + w * 8 + rr) * 512 + gsw * 8;
        lb[rp] = Bs + (rp * 64 + w * 8) * 64;  // wave-uniform; HW adds lane*16B
    }
    // issue Bs stage for kt=0 now -> overlaps with the whole gather phase
#pragma unroll
    for (int rp = 0; rp < 4; rp++) {
        __builtin_amdgcn_global_load_lds(
            (const __attribute__((address_space(1))) unsigned*)gb[rp],
            (__attribute__((address_space(3))) unsigned*)lb[rp], 16, 0, 0);
        gb[rp] += 64;
    }

    // ---- gather phase: 1 row per wave per pass, 8-deep batches ----
    const int c = lane;        // k-granule 0..63 (feats c*8..c*8+7)
    const ushort_t* gc_ = g + c * 8;
    float4 bv0 = *(const float4*)(b1_s + c * 8);
    float4 bv1 = *(const float4*)(b1_s + c * 8 + 4);

#pragma unroll
    for (int p = 0; p < 4; p++) {
        const int rP = p * 8 + w;
        const int cntR = cnt_s[rP];
        const float pdr = __builtin_bit_cast(float, adj_s[rP][0].y);
        const int selfR = adj_s[rP][0].x;

        float a0 = 0.f, a1 = 0.f, a2 = 0.f, a3 = 0.f;
        float a4 = 0.f, a5 = 0.f, a6 = 0.f, a7 = 0.f;

        for (int e0 = 0; e0 < cntR; e0 += 8) {
            int2 cp[8];
#pragma unroll
            for (int j = 0; j < 8; j++) cp[j] = adj_s[rP][e0 + j];
            uint4 u[8];
#pragma unroll
            for (int j = 0; j < 8; j++)
                u[j] = *(const uint4*)(gc_ + (size_t)cp[j].x * 512);
#pragma unroll
            for (int j = 0; j < 8; j++) {
                float ps = __builtin_bit_cast(float, cp[j].y);
                a0 = fmaf(ps, bf_lo(u[j].x), a0);
                a1 = fmaf(ps, bf_hi(u[j].x), a1);
                a2 = fmaf(ps, bf_lo(u[j].y), a2);
                a3 = fmaf(ps, bf_hi(u[j].y), a3);
                a4 = fmaf(ps, bf_lo(u[j].z), a4);
                a5 = fmaf(ps, bf_hi(u[j].z), a5);
                a6 = fmaf(ps, bf_lo(u[j].w), a6);
                a7 = fmaf(ps, bf_hi(u[j].w), a7);
            }
        }
        for (int k2 = 0; k2 < nov; k2++) {  // ~never taken
            if (ovf[2 * k2] == selfR) {
                int sI = ovf[2 * k2 + 1];
                float ps = dinv[sI];
                uint4 u = *(const uint4*)(gc_ + (size_t)sI * 512);
                a0 = fmaf(ps, bf_lo(u.x), a0);
                a1 = fmaf(ps, bf_hi(u.x), a1);
                a2 = fmaf(ps, bf_lo(u.y), a2);
                a3 = fmaf(ps, bf_hi(u.y), a3);
                a4 = fmaf(ps, bf_lo(u.z), a4);
                a5 = fmaf(ps, bf_hi(u.z), a5);
                a6 = fmaf(ps, bf_lo(u.w), a6);
                a7 = fmaf(ps, bf_hi(u.w), a7);
            }
        }
        float h0 = fmaxf(fmaf(pdr, a0, bv0.x), 0.0f);
        float h1 = fmaxf(fmaf(pdr, a1, bv0.y), 0.0f);
        float h2 = fmaxf(fmaf(pdr, a2, bv0.z), 0.0f);
        float h3 = fmaxf(fmaf(pdr, a3, bv0.w), 0.0f);
        float h4 = fmaxf(fmaf(pdr, a4, bv1.x), 0.0f);
        float h5 = fmaxf(fmaf(pdr, a5, bv1.y), 0.0f);
        float h6 = fmaxf(fmaf(pdr, a6, bv1.z), 0.0f);
        float h7 = fmaxf(fmaf(pdr, a7, bv1.w), 0.0f);
        uint4 U;
        U.x = pk2(h0, h1);
        U.y = pk2(h2, h3);
        U.z = pk2(h4, h5);
        U.w = pk2(h6, h7);
        int pos = (c & ~7) | ((c & 7) ^ (rP & 7));
        *(uint4*)(As + rP * 512 + pos * 8) = U;  // 2-way -> conflict-free
    }

    // ---- MFMA phase: As fixed, stream Bs per kt ----
    const int sel = ml & 7;
    int aoffb[2], boff[2][4];
#pragma unroll
    for (int st = 0; st < 2; st++) {
        aoffb[st] = (wm + ml) * 512 + (((st * 4 + q) ^ sel) << 3);
#pragma unroll
        for (int i = 0; i < 4; i++)
            boff[st][i] = (wn + i * 16 + ml) * 64 + (((q + st * 4) ^ sel) << 3);
    }
    floatx4 accm[4];
#pragma unroll
    for (int j = 0; j < 4; j++) accm[j] = (floatx4)0.0f;

    for (int kt = 0; kt < 8; kt++) {
        __syncthreads();  // Bs[kt] staged (vmcnt drained) + As visible (kt=0)
#pragma unroll
        for (int st = 0; st < 2; st++) {
            bf16x8 af = *(const bf16x8*)(As + aoffb[st] + kt * 64);
#pragma unroll
            for (int j = 0; j < 4; j++) {
                bf16x8 bfr = *(const bf16x8*)(Bs + boff[st][j]);
                accm[j] = __builtin_amdgcn_mfma_f32_16x16x32_bf16(af, bfr,
                                                                  accm[j], 0, 0, 0);
            }
        }
        __syncthreads();  // all waves done reading Bs[kt]
        if (kt < 7) {
#pragma unroll
            for (int rp = 0; rp < 4; rp++) {
                __builtin_amdgcn_global_load_lds(
                    (const __attribute__((address_space(1))) unsigned*)gb[rp],
                    (__attribute__((address_space(3))) unsigned*)lb[rp], 16, 0, 0);
                gb[rp] += 64;
            }
        }
    }

    // epilogue: C 32x256; row=wm+q*4+r, col=wn+j*16+ml; scale by dinv
#pragma unroll
    for (int j = 0; j < 4; j++) {
        int gcx = wn + j * 16 + ml;
#pragma unroll
        for (int rg = 0; rg < 4; rg++) {
            int lrow = wm + q * 4 + rg;
            int grow = row0 + lrow;
            if (grow < M) {
                float pd = __builtin_bit_cast(float, adj_s[lrow][0].y);
                g2[(size_t)grow * 256 + gcx] = f2bf(pd * accm[j][rg]);
            }
        }
    }
}

// Layer-2 aggregate over PRE-SCALED g2: out = relu(pd*(g[d]+sum g[s]) + b)
// g: [n][256] bf16 as uint2; one wave per node; cols preloaded once.
__global__ __launch_bounds__(64) void aggregate2(const uint2* __restrict__ g,
                                                 const int* __restrict__ deg,
                                                 const int* __restrict__ col_ell,
                                                 const int* __restrict__ ovf_cnt,
                                                 const int* __restrict__ ovf,
                                                 const float* __restrict__ dinv,
                                                 const float* __restrict__ bias,
                                                 float* __restrict__ out) {
    const int d = blockIdx.x, t = threadIdx.x;
    const int cnt = min(deg[d], MAXD);
    const float pd = dinv[d];
    const size_t base = (size_t)d * 64 + t;
    const int* cm = col_ell + (size_t)d * MAXD;

    int cv = 0;
    float wv = 0.0f;
    if (t < MAXD && t < cnt) {
        cv = cm[t];
        wv = 1.0f;
    }
    float4 b = *(const float4*)(bias + t * 4);

    uint2 us = g[base];
    float a0 = bf_lo(us.x), a1 = bf_hi(us.x);
    float a2 = bf_lo(us.y), a3 = bf_hi(us.y);  // self term

    for (int e0 = 0; e0 < cnt; e0 += 8) {
        uint2 u[8];
        float ws[8];
#pragma unroll
        for (int j = 0; j < 8; j++) {
            int s = __shfl(cv, e0 + j);
            ws[j] = __shfl(wv, e0 + j);
            u[j] = g[(size_t)s * 64 + t];
        }
#pragma unroll
        for (int j = 0; j < 8; j++) {
            a0 = fmaf(ws[j], bf_lo(u[j].x), a0);
            a1 = fmaf(ws[j], bf_hi(u[j].x), a1);
            a2 = fmaf(ws[j], bf_lo(u[j].y), a2);
            a3 = fmaf(ws[j], bf_hi(u[j].y), a3);
        }
    }
    int nov = *ovf_cnt;  // ~always 0
    for (int k = 0; k < nov; k++) {
        if (ovf[2 * k] == d) {
            uint2 u = g[(size_t)ovf[2 * k + 1] * 64 + t];
            a0 += bf_lo(u.x); a1 += bf_hi(u.x);
            a2 += bf_lo(u.y); a3 += bf_hi(u.y);
        }
    }
    float4 o;
    o.x = fmaxf(fmaf(pd, a0, b.x), 0.0f);
    o.y = fmaxf(fmaf(pd, a1, b.y), 0.0f);
    o.z = fmaxf(fmaf(pd, a2, b.z), 0.0f);
    o.w = fmaxf(fmaf(pd, a3, b.w), 0.0f);
    *(float4*)(out + (size_t)d * 256 + t * 4) = o;
}

extern "C" void kernel_launch(void* const* d_in, const int* in_sizes, int n_in,
                              void* d_out, int out_size, void* d_ws, size_t ws_size,
                              hipStream_t stream) {
    const float* x  = (const float*)d_in[0];
    const int*   ei = (const int*)d_in[1];   // int32 on device
    const float* W1 = (const float*)d_in[2];
    const float* b1 = (const float*)d_in[3];
    const float* W2 = (const float*)d_in[4];
    const float* b2 = (const float*)d_in[5];
    float* out = (float*)d_out;

    const int FIN = 512, FH = 512, FOUT = 256;
    const int n = in_sizes[0] / FIN;  // 20000
    const int e = in_sizes[1] / 2;    // 160000
    const int* src = ei;
    const int* dst = ei + e;

    auto align_up = [](size_t v) { return (v + 255) & ~(size_t)255; };
    char* w = (char*)d_ws;
    int*      deg     = (int*)w;                 // deg[n] + ovf_cnt adjacent
    int*      ovf_cnt = deg + n;
    w += align_up((size_t)(n + 1) * 4);
    float*    dinv    = (float*)w;    w += align_up((size_t)n * 4);
    int*      col_ell = (int*)w;      w += align_up((size_t)n * MAXD * 4);
    int*      ovf     = (int*)w;      w += align_up((size_t)2048 * 4);
    ushort_t* xb      = (ushort_t*)w; w += align_up((size_t)n * FIN * 2);
    ushort_t* w1t     = (ushort_t*)w; w += align_up((size_t)FH * FIN * 2);
    ushort_t* w2t     = (ushort_t*)w; w += align_up((size_t)FOUT * FH * 2);
    ushort_t* g       = (ushort_t*)w; w += align_up((size_t)n * FH * 2);   // x@W1
    ushort_t* g2      = (ushort_t*)w; w += align_up((size_t)n * FOUT * 2); // scaled h1@W2

    const int nb_n = (n + 255) / 256;
    const int nb_e = (e + 255) / 256;
    const long xcount = (long)n * FIN;
    const int nb_conv = (int)((xcount / 4 + 255) / 256);

    hipMemsetAsync(deg, 0, (size_t)(n + 1) * 4, stream);  // deg + ovf_cnt

    prep_fused<<<nb_e + nb_conv + 256 + 128, 256, 0, stream>>>(
        src, dst, deg, col_ell, ovf_cnt, ovf, e, nb_e,
        x, xb, xcount, nb_conv, W1, w1t, W2, w2t);

    // layer 1 GEMM (unscaled) + dinv tail blocks
    {
        const int mb = (n + 127) / 128;
        int gemm_blocks = (FH / 128) * mb;
        gemm_mfma<<<gemm_blocks + nb_n, 256, 0, stream>>>(
            xb, w1t, g, n, FH, FIN, FH / 128, gemm_blocks, deg, dinv, n);
    }
    // fused aggregate1 + layer-2 GEMM (writes pre-scaled g2), BM=32, 512 thr
    agg1gemm2<<<(n + 31) / 32, 512, 0, stream>>>(
        g, w2t, deg, col_ell, ovf_cnt, ovf, dinv, b1, g2, n);

    aggregate2<<<n, 64, 0, stream>>>((const uint2*)g2, deg, col_ell, ovf_cnt,
                                     ovf, dinv, b2, out);

    (void)ws_size; (void)n_in; (void)out_size;
}